// Round 14
// baseline (53.078 us; speedup 1.0000x reference)
//
#include <hip/hip_runtime.h>
#include <hip/hip_bf16.h>

// Problem constants (fixed by setup_inputs): B=4, S=8192, D=1024, E=64, top_k=1
#define NB 4
#define NS 8192
#define ND 1024
#define NE 64
#define NM (NB * NS)          // 32768 tokens
#define CAPACITY 640

#define BM 128                // tokens per k1 block == hist chunk size
#define BK 64                 // K-tile
#define NKT (ND / BK)         // 16 K-tiles
#define NBLK (NM / BM)        // 256 blocks -> exactly 1/CU (LDS-limited)
#define CPB (NS / BM)         // 64 chunks per batch

#define OCH 128               // tokens per output block (== hist chunk)
#define NOB (NM / OCH)        // 256 output blocks

typedef short short8 __attribute__((ext_vector_type(8)));
typedef float f32x4 __attribute__((ext_vector_type(4)));

#define GLOAD16(g, l)                                                          \
    __builtin_amdgcn_global_load_lds(                                          \
        (const __attribute__((address_space(1))) void*)(g),                    \
        (__attribute__((address_space(3))) void*)(l), 16, 0, 0)

// ---------------------------------------------------------------------------
// K1: async-DMA bf16x3-split MFMA GEMM + fused softmax-top1.
// r13 skeleton scaled to BM=128 / 512 threads / 1 block/CU:
//   - W traffic + W-split VALU halve per token; barriers halve per token.
//   - x: gload_lds, 3 buffers (staged 2 ahead). W: gload_lds, 2 buffers.
//   - Per-wave per tile: 4 x-units + 2 W-units; steady wait vmcnt(10)
//     (in flight: x(kt+1) 4, W(kt+1) 2, x(kt+2) 4).
// LDS 128 KB: xs[3]x32K [0,96K) | ws[2]x16K [96K,128K); sLog reuses [0,32K).
// Split math / MFMA order / swizzle identical to r10/r13 => bitwise-same
// logits (arow&15==lr, erow&15==lr hold for 8 waves too).
// Swizzle (rule #21): source 16B-unit ^ (row&15), un-XOR'd on ds_read side.
// C/D layout (verified m89/m91): col = lane&15 (expert), row = (lane>>4)*4+reg.
// ---------------------------------------------------------------------------
__global__ __launch_bounds__(512, 1) void k1_mfma(const float* __restrict__ x,
                                                  const float* __restrict__ W,
                                                  float* __restrict__ logits,
                                                  int* __restrict__ idx_ws,
                                                  float* __restrict__ prob_ws,
                                                  int* __restrict__ hist)
{
    __shared__ char SL[131072];
    __shared__ int lh[NE];

    const int tid = threadIdx.x;
    const int lane = tid & 63;
    const int wv = tid >> 6;          // 0..7
    const int lr = lane & 15;
    const int kq = lane >> 4;
    const int tok0 = blockIdx.x * BM;

    if (tid < NE) lh[tid] = 0;

    f32x4 acc[4];
#pragma unroll
    for (int j = 0; j < 4; ++j) acc[j] = (f32x4){0.f, 0.f, 0.f, 0.f};

    // ---- staging geometry ----
    // x tile [128 rows][16 units]: 32 instrs, wave w rows [w*16, +16), 4/wave.
    // W tile [64 rows][16 units]: 16 instrs, wave w rows [w*8, +8), 2/wave.
    const int lrow4 = lane >> 4;      // 0..3
    const int uslot = lane & 15;

    auto stage_x = [&](int kt) {
        const int k0 = kt * BK;
        char* dst = SL + (kt % 3) * 32768 + wv * 4096;
#pragma unroll
        for (int q = 0; q < 4; ++q) {
            const int r = wv * 16 + q * 4 + lrow4;
            const int su = uslot ^ (r & 15);
            const float* g = x + (size_t)(tok0 + r) * ND + k0 + su * 4;
            GLOAD16(g, dst + q * 1024);
        }
    };
    auto stage_w = [&](int kt) {
        const int k0 = kt * BK;
        char* dst = SL + 98304 + (kt & 1) * 16384 + wv * 2048;
#pragma unroll
        for (int q = 0; q < 2; ++q) {
            const int r = wv * 8 + q * 4 + lrow4;
            const int su = uslot ^ (r & 15);
            const float* g = W + (size_t)r * ND + k0 + su * 4;
            GLOAD16(g, dst + q * 1024);
        }
    };

    // ---- compute one K-tile from x buf kt%3, W buf kt&1 -------------------
    auto compute = [&](int kt) {
        const float* xsb = (const float*)(SL + (kt % 3) * 32768);
        const float* wsb = (const float*)(SL + 98304 + (kt & 1) * 16384);
        const int arow = wv * 16 + lr;        // arow&15 == lr
#pragma unroll
        for (int kk = 0; kk < 2; ++kk) {
            const int su = kk * 8 + kq * 2;
            f32x4 a0 = *(const f32x4*)&xsb[arow * 64 + ((su)     ^ lr) * 4];
            f32x4 a1 = *(const f32x4*)&xsb[arow * 64 + ((su + 1) ^ lr) * 4];
            float f[8] = {a0[0], a0[1], a0[2], a0[3], a1[0], a1[1], a1[2], a1[3]};
            short8 ah, al;
#pragma unroll
            for (int c = 0; c < 8; ++c) {
                unsigned int u = __builtin_bit_cast(unsigned int, f[c]);
                ah[c] = (short)(u >> 16);                         // trunc hi (as r5-r13)
                float fhi = __builtin_bit_cast(float, u & 0xFFFF0000u);
                __hip_bfloat16 lb = __float2bfloat16(f[c] - fhi); // RNE lo
                al[c] = __builtin_bit_cast(short, lb);
            }
#pragma unroll
            for (int j = 0; j < 4; ++j) {
                const int erow = j * 16 + lr;                     // erow&15 == lr
                f32x4 w0 = *(const f32x4*)&wsb[erow * 64 + ((su)     ^ lr) * 4];
                f32x4 w1 = *(const f32x4*)&wsb[erow * 64 + ((su + 1) ^ lr) * 4];
                float g[8] = {w0[0], w0[1], w0[2], w0[3], w1[0], w1[1], w1[2], w1[3]};
                short8 bh, bl;
#pragma unroll
                for (int c = 0; c < 8; ++c) {
                    __hip_bfloat16 hb = __float2bfloat16(g[c]);   // RNE hi (as r9-r13)
                    float r = g[c] - __bfloat162float(hb);
                    __hip_bfloat16 lb = __float2bfloat16(r);      // RNE lo
                    bh[c] = __builtin_bit_cast(short, hb);
                    bl[c] = __builtin_bit_cast(short, lb);
                }
                acc[j] = __builtin_amdgcn_mfma_f32_16x16x32_bf16(ah, bh, acc[j], 0, 0, 0);
                acc[j] = __builtin_amdgcn_mfma_f32_16x16x32_bf16(ah, bl, acc[j], 0, 0, 0);
                acc[j] = __builtin_amdgcn_mfma_f32_16x16x32_bf16(al, bh, acc[j], 0, 0, 0);
            }
        }
    };

    // ---- prologue: x(0) [4], W(0) [2], x(1) [4] = 10 in flight per wave ----
    stage_x(0);
    stage_w(0);
    stage_x(1);

    // ---- main loop ----
#pragma unroll
    for (int kt = 0; kt < NKT; ++kt) {
        if (kt + 1 < NKT) stage_w(kt + 1);
        if (kt + 2 < NKT) stage_x(kt + 2);
        // complete x(kt)+W(kt); leave [x(kt+1), W(kt+1), x(kt+2)] in flight
        if (kt < NKT - 2)       asm volatile("s_waitcnt vmcnt(10)" ::: "memory");
        else if (kt == NKT - 2) asm volatile("s_waitcnt vmcnt(6)"  ::: "memory");
        else                    asm volatile("s_waitcnt vmcnt(0)"  ::: "memory");
        __builtin_amdgcn_s_barrier();
        __builtin_amdgcn_sched_barrier(0);
        compute(kt);
        __builtin_amdgcn_sched_barrier(0);
        __builtin_amdgcn_s_barrier();          // reads of tile kt done
    }

    __syncthreads();   // full fence before reusing xs0 region as sLog

    float* sLog = (float*)SL;                  // [0,32K)

    // ---- fused epilogue: per-token softmax top-1 (each wave: its 16 tokens)
#pragma unroll
    for (int r = 0; r < 4; ++r) {
        const int tl = wv * 16 + kq * 4 + r;   // token local to block (0..127)
        float val[4];
#pragma unroll
        for (int j = 0; j < 4; ++j) val[j] = acc[j][r];

        // local argmax over j (ascending j + strict > keeps lowest expert)
        float m = val[0];
        int mi = lr;
#pragma unroll
        for (int j = 1; j < 4; ++j) {
            if (val[j] > m) { m = val[j]; mi = j * 16 + lr; }
        }
        // butterfly across the 16 lanes of this fragment-row group
#pragma unroll
        for (int off = 1; off < 16; off <<= 1) {
            float m2 = __shfl_xor(m, off);
            int mi2 = __shfl_xor(mi, off);
            if (m2 > m || (m2 == m && mi2 < mi)) { m = m2; mi = mi2; }
        }
        // softmax denominator
        float s = 0.0f;
#pragma unroll
        for (int j = 0; j < 4; ++j) s += __expf(val[j] - m);
#pragma unroll
        for (int off = 1; off < 16; off <<= 1) s += __shfl_xor(s, off);

        // stage logits in LDS for dense write
#pragma unroll
        for (int j = 0; j < 4; ++j) sLog[tl * NE + j * 16 + lr] = val[j];
        if (lr == 0) {
            idx_ws[tok0 + tl] = mi;
            prob_ws[tok0 + tl] = 1.0f / s;
            atomicAdd(&lh[mi], 1);
        }
    }
    __syncthreads();

    // dense logits write: 8192 floats = 4 passes x 512 thr x float4
    const size_t g0 = (size_t)tok0 * NE;
#pragma unroll
    for (int i = 0; i < 4; ++i) {
        const int fl = i * 2048 + tid * 4;
        *(float4*)&logits[g0 + fl] = *(const float4*)&sLog[fl];
    }
    if (tid < NE) hist[blockIdx.x * NE + tid] = lh[tid];
}

// ---------------------------------------------------------------------------
// K2: output kernel. One block per 128-token chunk (256 blocks x 256 thr):
//   base = sum of this batch's preceding chunk hists (4-wave strided),
//   ordered capacity rank (wave 0, lane = expert, INCLUSIVE <= CAPACITY),
//   dense float4 writes of e_out / p_out (no zero-fill, no RMW).
// ---------------------------------------------------------------------------
__global__ __launch_bounds__(256) void k_out(const int* __restrict__ idx_ws,
                                             const float* __restrict__ prob_ws,
                                             const int* __restrict__ hist,
                                             float* __restrict__ e_out,
                                             float* __restrict__ p_out)
{
    __shared__ int sMi[OCH];
    __shared__ float sPr[OCH];
    __shared__ int sAd[OCH];
    __shared__ int pp[4][NE];

    const int c = blockIdx.x;        // 0..255 == chunk id
    const int b = c >> 6;            // batch (64 chunks per batch)
    const int s = c & 63;            // chunk within batch
    const int t0 = c * OCH;
    const int tid = threadIdx.x;
    const int lane = tid & 63;
    const int wv = tid >> 6;

    if (tid < OCH) {
        sMi[tid] = idx_ws[t0 + tid];
        sPr[tid] = prob_ws[t0 + tid];
    }

    // strided partial sums over the batch's preceding s chunks
    {
        int run = 0;
        const int* hrow = hist + (size_t)(b * CPB) * NE + lane;
        for (int i = wv; i < s; i += 4) run += hrow[i * NE];
        pp[wv][lane] = run;
    }
    __syncthreads();

    if (wv == 0) {
        int run = pp[0][lane] + pp[1][lane] + pp[2][lane] + pp[3][lane];
        for (int j = 0; j < OCH; ++j) {
            if (sMi[j] == lane) { ++run; sAd[j] = (run <= CAPACITY) ? 1 : 0; }
        }
    }
    __syncthreads();

    // dense e/p writes: 8192 floats each = 8 passes x 256 thr x float4
    const size_t g0 = (size_t)t0 * NE;
#pragma unroll
    for (int i = 0; i < 8; ++i) {
        const int fl = i * 1024 + tid * 4;
        const int t = fl >> 6;
        const int e0 = fl & 63;
        const int mi = sMi[t];
        const float pr = sPr[t];
        const int ad = sAd[t];
        float4 ev, pv;
        float* evp = &ev.x;
        float* pvp = &pv.x;
#pragma unroll
        for (int cc = 0; cc < 4; ++cc) {
            const bool hit = (mi == e0 + cc) && ad;
            evp[cc] = hit ? 1.0f : 0.0f;
            pvp[cc] = hit ? pr : 0.0f;
        }
        *(float4*)&e_out[g0 + fl] = ev;
        *(float4*)&p_out[g0 + fl] = pv;
    }
}

// ---------------------------------------------------------------------------
extern "C" void kernel_launch(void* const* d_in, const int* in_sizes, int n_in,
                              void* d_out, int out_size, void* d_ws, size_t ws_size,
                              hipStream_t stream)
{
    const float* x = (const float*)d_in[0];   // [B,S,D] fp32
    const float* W = (const float*)d_in[1];   // [E,D] fp32
    // d_in[2] = top_k (==1), ignored

    float* out = (float*)d_out;
    float* e_out = out;                          // expert_indices as 0.0/1.0
    float* p_out = out + (size_t)NM * NE;        // router_probs
    float* logits = out + 2 * (size_t)NM * NE;   // logits

    char* ws = (char*)d_ws;
    int* idx_ws    = (int*)ws;                                   // 128 KB
    float* prob_ws = (float*)(ws + (size_t)NM * 4);              // 128 KB
    int* hist      = (int*)(ws + (size_t)NM * 8);                // 256*64*4 = 64 KB

    k1_mfma<<<NBLK, 512, 0, stream>>>(x, W, logits, idx_ws, prob_ws, hist);
    k_out<<<NOB, 256, 0, stream>>>(idx_ws, prob_ws, hist, e_out, p_out);
}

// Round 15
// 46.710 us; speedup vs baseline: 1.1363x; 1.1363x over previous
//
#include <hip/hip_runtime.h>
#include <hip/hip_bf16.h>

// Problem constants (fixed by setup_inputs): B=4, S=8192, D=1024, E=64, top_k=1
#define NB 4
#define NS 8192
#define ND 1024
#define NE 64
#define NM (NB * NS)          // 32768 tokens
#define CAPACITY 640

#define BM 64                 // tokens per k1 block == hist chunk size
#define BK 64                 // K-tile
#define NKT (ND / BK)         // 16 K-tiles
#define NBLK (NM / BM)        // 512 blocks -> 2/CU, all resident
#define CPB (NS / BM)         // 128 chunks per batch

#define OCH 64                // tokens per output block
#define NOB (NM / OCH)        // 512 output blocks

typedef short short8 __attribute__((ext_vector_type(8)));
typedef float f32x4 __attribute__((ext_vector_type(4)));

#define GLOAD16(g, l)                                                          \
    __builtin_amdgcn_global_load_lds(                                          \
        (const __attribute__((address_space(1))) void*)(g),                    \
        (__attribute__((address_space(3))) void*)(l), 16, 0, 0)

// ---------------------------------------------------------------------------
// K1: async-DMA bf16x3-split MFMA GEMM + fused softmax-top1.
// r13 data layout, SINGLE-BARRIER schedule (8-phase-lite):
//   iter kt: wait vmcnt(4) -> s_barrier -> stage_W(kt+1) -> compute(kt)
//            -> stage_x(kt+2)
//   - ONE sync point per K-tile (r13 had two). Buffer safety: the buffer
//     stage_x(kt+2) overwrites held x(kt-1), whose readers finished
//     compute(kt-1) BEFORE this iter's barrier; same for W(kt+1) over W(kt-1).
//   - W(kt+1) issue precedes compute(kt) -> L2 latency hidden under compute.
//   - x staged 2 ahead (3 buffers); steady wait leaves x(kt+2) in flight
//     (vmcnt(4)), never 0 mid-loop.
// LDS 80 KB: xs[3]x16K [0,48K) | ws[2]x16K [48K,80K) -> 2 blocks/CU.
// sLog reuses [0,16K), lh reuses [16K,+256) at epilogue.
// Split math / MFMA order / swizzle identical to r10/r13 => bitwise-same
// logits. Swizzle (rule #21): source 16B-unit ^ (row&15), un-XOR'd on the
// ds_read side. C/D layout (m89/m91): col = lane&15, row = (lane>>4)*4+reg.
// ---------------------------------------------------------------------------
__global__ __launch_bounds__(256, 2) void k1_mfma(const float* __restrict__ x,
                                                  const float* __restrict__ W,
                                                  float* __restrict__ logits,
                                                  int* __restrict__ idx_ws,
                                                  float* __restrict__ prob_ws,
                                                  int* __restrict__ hist)
{
    __shared__ char SL[81920];

    const int tid = threadIdx.x;
    const int lane = tid & 63;
    const int wv = tid >> 6;          // 0..3
    const int lr = lane & 15;
    const int kq = lane >> 4;
    const int tok0 = blockIdx.x * BM;

    f32x4 acc[4];
#pragma unroll
    for (int j = 0; j < 4; ++j) acc[j] = (f32x4){0.f, 0.f, 0.f, 0.f};

    // staging geometry (x and W identical): wave w covers rows [w*16,+16),
    // 4 instrs (q=0..3); lane l -> row r = w*16 + q*4 + (l>>4),
    // source 16B-unit = (l&15) ^ (r&15); LDS dst = buf + (w*16+q*4)*256.
    const int srow = wv * 16 + (lane >> 4);   // + q*4
    const int uslot = lane & 15;

    auto stage_x = [&](int kt) {
        const int k0 = kt * BK;
        char* dst = SL + (kt % 3) * 16384 + wv * 4096;
#pragma unroll
        for (int q = 0; q < 4; ++q) {
            const int r = srow + q * 4;
            const int su = uslot ^ (r & 15);
            const float* g = x + (size_t)(tok0 + r) * ND + k0 + su * 4;
            GLOAD16(g, dst + q * 1024);
        }
    };
    auto stage_w = [&](int kt) {
        const int k0 = kt * BK;
        char* dst = SL + 49152 + (kt & 1) * 16384 + wv * 4096;
#pragma unroll
        for (int q = 0; q < 4; ++q) {
            const int r = srow + q * 4;
            const int su = uslot ^ (r & 15);
            const float* g = W + (size_t)r * ND + k0 + su * 4;
            GLOAD16(g, dst + q * 1024);
        }
    };

    // ---- compute one K-tile from x buf kt%3, W buf kt&1 -------------------
    auto compute = [&](int kt) {
        const float* xsb = (const float*)(SL + (kt % 3) * 16384);
        const float* wsb = (const float*)(SL + 49152 + (kt & 1) * 16384);
        const int arow = wv * 16 + lr;        // arow&15 == lr
#pragma unroll
        for (int kk = 0; kk < 2; ++kk) {
            const int su = kk * 8 + kq * 2;
            f32x4 a0 = *(const f32x4*)&xsb[arow * 64 + ((su)     ^ lr) * 4];
            f32x4 a1 = *(const f32x4*)&xsb[arow * 64 + ((su + 1) ^ lr) * 4];
            float f[8] = {a0[0], a0[1], a0[2], a0[3], a1[0], a1[1], a1[2], a1[3]};
            short8 ah, al;
#pragma unroll
            for (int c = 0; c < 8; ++c) {
                unsigned int u = __builtin_bit_cast(unsigned int, f[c]);
                ah[c] = (short)(u >> 16);                         // trunc hi (as r5-r13)
                float fhi = __builtin_bit_cast(float, u & 0xFFFF0000u);
                __hip_bfloat16 lb = __float2bfloat16(f[c] - fhi); // RNE lo
                al[c] = __builtin_bit_cast(short, lb);
            }
#pragma unroll
            for (int j = 0; j < 4; ++j) {
                const int erow = j * 16 + lr;                     // erow&15 == lr
                f32x4 w0 = *(const f32x4*)&wsb[erow * 64 + ((su)     ^ lr) * 4];
                f32x4 w1 = *(const f32x4*)&wsb[erow * 64 + ((su + 1) ^ lr) * 4];
                float g[8] = {w0[0], w0[1], w0[2], w0[3], w1[0], w1[1], w1[2], w1[3]};
                short8 bh, bl;
#pragma unroll
                for (int c = 0; c < 8; ++c) {
                    __hip_bfloat16 hb = __float2bfloat16(g[c]);   // RNE hi (as r9-r13)
                    float r = g[c] - __bfloat162float(hb);
                    __hip_bfloat16 lb = __float2bfloat16(r);      // RNE lo
                    bh[c] = __builtin_bit_cast(short, hb);
                    bl[c] = __builtin_bit_cast(short, lb);
                }
                acc[j] = __builtin_amdgcn_mfma_f32_16x16x32_bf16(ah, bh, acc[j], 0, 0, 0);
                acc[j] = __builtin_amdgcn_mfma_f32_16x16x32_bf16(ah, bl, acc[j], 0, 0, 0);
                acc[j] = __builtin_amdgcn_mfma_f32_16x16x32_bf16(al, bh, acc[j], 0, 0, 0);
            }
        }
    };

    // ---- prologue: x(0), W(0), x(1)  (12 outstanding per wave) ----
    stage_x(0);
    stage_w(0);
    stage_x(1);

    // ---- main loop: ONE barrier per tile ----
#pragma unroll
    for (int kt = 0; kt < NKT; ++kt) {
        // complete x(kt)+W(kt); steady state leaves x(kt+1-in-bufs… actually
        // the 4 newest loads (next x stage) in flight
        if (kt < NKT - 1) asm volatile("s_waitcnt vmcnt(4)" ::: "memory");
        else              asm volatile("s_waitcnt vmcnt(0)" ::: "memory");
        __builtin_amdgcn_s_barrier();          // all waves done with tile kt-1
        __builtin_amdgcn_sched_barrier(0);
        if (kt + 1 < NKT) stage_w(kt + 1);     // hidden under compute(kt)
        __builtin_amdgcn_sched_barrier(0);
        compute(kt);
        __builtin_amdgcn_sched_barrier(0);
        if (kt + 2 < NKT) stage_x(kt + 2);     // buf (kt+2)%3 free since barrier
    }

    __syncthreads();   // full fence before reusing x buffers

    float* sLog = (float*)SL;                  // [0,16K)
    int* lh = (int*)(SL + 16384);              // xs1 region, dead now

    if (tid < NE) lh[tid] = 0;
    __syncthreads();

    // ---- fused epilogue: per-token softmax top-1 (each wave: its 16 tokens)
#pragma unroll
    for (int r = 0; r < 4; ++r) {
        const int tl = wv * 16 + kq * 4 + r;   // token local to block (0..63)
        float val[4];
#pragma unroll
        for (int j = 0; j < 4; ++j) val[j] = acc[j][r];

        // local argmax over j (ascending j + strict > keeps lowest expert)
        float m = val[0];
        int mi = lr;
#pragma unroll
        for (int j = 1; j < 4; ++j) {
            if (val[j] > m) { m = val[j]; mi = j * 16 + lr; }
        }
        // butterfly across the 16 lanes of this fragment-row group
#pragma unroll
        for (int off = 1; off < 16; off <<= 1) {
            float m2 = __shfl_xor(m, off);
            int mi2 = __shfl_xor(mi, off);
            if (m2 > m || (m2 == m && mi2 < mi)) { m = m2; mi = mi2; }
        }
        // softmax denominator
        float s = 0.0f;
#pragma unroll
        for (int j = 0; j < 4; ++j) s += __expf(val[j] - m);
#pragma unroll
        for (int off = 1; off < 16; off <<= 1) s += __shfl_xor(s, off);

        // stage logits in LDS for dense write
#pragma unroll
        for (int j = 0; j < 4; ++j) sLog[tl * NE + j * 16 + lr] = val[j];
        if (lr == 0) {
            idx_ws[tok0 + tl] = mi;
            prob_ws[tok0 + tl] = 1.0f / s;
            atomicAdd(&lh[mi], 1);
        }
    }
    __syncthreads();

    // dense logits write: 4096 floats = 4 passes x 256 thr x float4
    const size_t g0 = (size_t)tok0 * NE;
#pragma unroll
    for (int i = 0; i < 4; ++i) {
        const int fl = i * 1024 + tid * 4;
        *(float4*)&logits[g0 + fl] = *(const float4*)&sLog[fl];
    }
    if (tid < NE) hist[blockIdx.x * NE + tid] = lh[tid];
}

// ---------------------------------------------------------------------------
// K2: output kernel. One block per 64-token chunk (512 blocks x 256 thr):
//   base = sum of this batch's preceding chunk hists (4-wave strided),
//   ordered capacity rank (wave 0, lane = expert, INCLUSIVE <= CAPACITY),
//   dense float4 writes of e_out / p_out (no zero-fill, no RMW).
// ---------------------------------------------------------------------------
__global__ __launch_bounds__(256) void k_out(const int* __restrict__ idx_ws,
                                             const float* __restrict__ prob_ws,
                                             const int* __restrict__ hist,
                                             float* __restrict__ e_out,
                                             float* __restrict__ p_out)
{
    __shared__ int sMi[OCH];
    __shared__ float sPr[OCH];
    __shared__ int sAd[OCH];
    __shared__ int pp[4][NE];

    const int c = blockIdx.x;        // 0..511 == chunk id
    const int b = c >> 7;            // batch (128 chunks per batch)
    const int s = c & 127;           // chunk within batch
    const int t0 = c * OCH;
    const int tid = threadIdx.x;
    const int lane = tid & 63;
    const int wv = tid >> 6;

    if (tid < OCH) {
        sMi[tid] = idx_ws[t0 + tid];
        sPr[tid] = prob_ws[t0 + tid];
    }

    // strided partial sums over the batch's preceding s chunks
    {
        int run = 0;
        const int* hrow = hist + (size_t)(b * CPB) * NE + lane;
        for (int i = wv; i < s; i += 4) run += hrow[i * NE];
        pp[wv][lane] = run;
    }
    __syncthreads();

    if (wv == 0) {
        int run = pp[0][lane] + pp[1][lane] + pp[2][lane] + pp[3][lane];
        for (int j = 0; j < OCH; ++j) {
            if (sMi[j] == lane) { ++run; sAd[j] = (run <= CAPACITY) ? 1 : 0; }
        }
    }
    __syncthreads();

    // dense e/p writes: 4096 floats each = 4 passes x 256 thr x float4
    const size_t g0 = (size_t)t0 * NE;
#pragma unroll
    for (int i = 0; i < 4; ++i) {
        const int fl = i * 1024 + tid * 4;
        const int t = fl >> 6;
        const int e0 = fl & 63;
        const int mi = sMi[t];
        const float pr = sPr[t];
        const int ad = sAd[t];
        float4 ev, pv;
        float* evp = &ev.x;
        float* pvp = &pv.x;
#pragma unroll
        for (int cc = 0; cc < 4; ++cc) {
            const bool hit = (mi == e0 + cc) && ad;
            evp[cc] = hit ? 1.0f : 0.0f;
            pvp[cc] = hit ? pr : 0.0f;
        }
        *(float4*)&e_out[g0 + fl] = ev;
        *(float4*)&p_out[g0 + fl] = pv;
    }
}

// ---------------------------------------------------------------------------
extern "C" void kernel_launch(void* const* d_in, const int* in_sizes, int n_in,
                              void* d_out, int out_size, void* d_ws, size_t ws_size,
                              hipStream_t stream)
{
    const float* x = (const float*)d_in[0];   // [B,S,D] fp32
    const float* W = (const float*)d_in[1];   // [E,D] fp32
    // d_in[2] = top_k (==1), ignored

    float* out = (float*)d_out;
    float* e_out = out;                          // expert_indices as 0.0/1.0
    float* p_out = out + (size_t)NM * NE;        // router_probs
    float* logits = out + 2 * (size_t)NM * NE;   // logits

    char* ws = (char*)d_ws;
    int* idx_ws    = (int*)ws;                                   // 128 KB
    float* prob_ws = (float*)(ws + (size_t)NM * 4);              // 128 KB
    int* hist      = (int*)(ws + (size_t)NM * 8);                // 512*64*4 = 128 KB

    k1_mfma<<<NBLK, 256, 0, stream>>>(x, W, logits, idx_ws, prob_ws, hist);
    k_out<<<NOB, 256, 0, stream>>>(idx_ws, prob_ws, hist, e_out, p_out);
}

// Round 16
// 46.476 us; speedup vs baseline: 1.1421x; 1.0050x over previous
//
#include <hip/hip_runtime.h>
#include <hip/hip_bf16.h>

// Problem constants (fixed by setup_inputs): B=4, S=8192, D=1024, E=64, top_k=1
#define NB 4
#define NS 8192
#define ND 1024
#define NE 64
#define NM (NB * NS)          // 32768 tokens
#define CAPACITY 640

#define BM 64                 // tokens per k1 block == hist chunk size
#define BK 64                 // K-tile
#define NKT (ND / BK)         // 16 K-tiles
#define NBLK (NM / BM)        // 512 blocks -> 2/CU, all resident
#define CPB (NS / BM)         // 128 chunks per batch

#define OCH 64                // tokens per output block
#define NOB (NM / OCH)        // 512 output blocks

typedef short short8 __attribute__((ext_vector_type(8)));
typedef float f32x4 __attribute__((ext_vector_type(4)));

#define GLOAD16(g, l)                                                          \
    __builtin_amdgcn_global_load_lds(                                          \
        (const __attribute__((address_space(1))) void*)(g),                    \
        (__attribute__((address_space(3))) void*)(l), 16, 0, 0)

// ---------------------------------------------------------------------------
// K1: async-DMA bf16x3-split MFMA GEMM + fused softmax-top1.
// r15 single-barrier schedule + T5 setprio around compute + relaxed fence
// between stage_W and compute (stage_w's dest buffer is untouched until the
// NEXT barrier, so compiler may interleave its VMEM issues with compute).
//   iter kt: wait vmcnt(4) -> s_barrier -> stage_W(kt+1) ∥ compute(kt)
//            -> stage_x(kt+2)    [stage_x fences stay pinned: its dest is
//                                 buf (kt+2)%3 == (kt-1)%3, freed by barrier]
// LDS 80 KB: xs[3]x16K [0,48K) | ws[2]x16K [48K,80K) -> 2 blocks/CU.
// sLog reuses [0,16K), lh reuses [16K,+256) at epilogue.
// Split math / MFMA order / swizzle identical to r10-r15 => bitwise-same
// logits. Swizzle (rule #21): source 16B-unit ^ (row&15), un-XOR'd on the
// ds_read side. C/D layout (m89/m91): col = lane&15, row = (lane>>4)*4+reg.
// ---------------------------------------------------------------------------
__global__ __launch_bounds__(256, 2) void k1_mfma(const float* __restrict__ x,
                                                  const float* __restrict__ W,
                                                  float* __restrict__ logits,
                                                  int* __restrict__ idx_ws,
                                                  float* __restrict__ prob_ws,
                                                  int* __restrict__ hist)
{
    __shared__ char SL[81920];

    const int tid = threadIdx.x;
    const int lane = tid & 63;
    const int wv = tid >> 6;          // 0..3
    const int lr = lane & 15;
    const int kq = lane >> 4;
    const int tok0 = blockIdx.x * BM;

    f32x4 acc[4];
#pragma unroll
    for (int j = 0; j < 4; ++j) acc[j] = (f32x4){0.f, 0.f, 0.f, 0.f};

    // staging geometry (x and W identical): wave w covers rows [w*16,+16),
    // 4 instrs (q=0..3); lane l -> row r = w*16 + q*4 + (l>>4),
    // source 16B-unit = (l&15) ^ (r&15); LDS dst = buf + (w*16+q*4)*256.
    const int srow = wv * 16 + (lane >> 4);   // + q*4
    const int uslot = lane & 15;

    auto stage_x = [&](int kt) {
        const int k0 = kt * BK;
        char* dst = SL + (kt % 3) * 16384 + wv * 4096;
#pragma unroll
        for (int q = 0; q < 4; ++q) {
            const int r = srow + q * 4;
            const int su = uslot ^ (r & 15);
            const float* g = x + (size_t)(tok0 + r) * ND + k0 + su * 4;
            GLOAD16(g, dst + q * 1024);
        }
    };
    auto stage_w = [&](int kt) {
        const int k0 = kt * BK;
        char* dst = SL + 49152 + (kt & 1) * 16384 + wv * 4096;
#pragma unroll
        for (int q = 0; q < 4; ++q) {
            const int r = srow + q * 4;
            const int su = uslot ^ (r & 15);
            const float* g = W + (size_t)r * ND + k0 + su * 4;
            GLOAD16(g, dst + q * 1024);
        }
    };

    // ---- compute one K-tile from x buf kt%3, W buf kt&1 -------------------
    auto compute = [&](int kt) {
        const float* xsb = (const float*)(SL + (kt % 3) * 16384);
        const float* wsb = (const float*)(SL + 49152 + (kt & 1) * 16384);
        const int arow = wv * 16 + lr;        // arow&15 == lr
#pragma unroll
        for (int kk = 0; kk < 2; ++kk) {
            const int su = kk * 8 + kq * 2;
            f32x4 a0 = *(const f32x4*)&xsb[arow * 64 + ((su)     ^ lr) * 4];
            f32x4 a1 = *(const f32x4*)&xsb[arow * 64 + ((su + 1) ^ lr) * 4];
            float f[8] = {a0[0], a0[1], a0[2], a0[3], a1[0], a1[1], a1[2], a1[3]};
            short8 ah, al;
#pragma unroll
            for (int c = 0; c < 8; ++c) {
                unsigned int u = __builtin_bit_cast(unsigned int, f[c]);
                ah[c] = (short)(u >> 16);                         // trunc hi (as r5-r15)
                float fhi = __builtin_bit_cast(float, u & 0xFFFF0000u);
                __hip_bfloat16 lb = __float2bfloat16(f[c] - fhi); // RNE lo
                al[c] = __builtin_bit_cast(short, lb);
            }
#pragma unroll
            for (int j = 0; j < 4; ++j) {
                const int erow = j * 16 + lr;                     // erow&15 == lr
                f32x4 w0 = *(const f32x4*)&wsb[erow * 64 + ((su)     ^ lr) * 4];
                f32x4 w1 = *(const f32x4*)&wsb[erow * 64 + ((su + 1) ^ lr) * 4];
                float g[8] = {w0[0], w0[1], w0[2], w0[3], w1[0], w1[1], w1[2], w1[3]};
                short8 bh, bl;
#pragma unroll
                for (int c = 0; c < 8; ++c) {
                    __hip_bfloat16 hb = __float2bfloat16(g[c]);   // RNE hi (as r9-r15)
                    float r = g[c] - __bfloat162float(hb);
                    __hip_bfloat16 lb = __float2bfloat16(r);      // RNE lo
                    bh[c] = __builtin_bit_cast(short, hb);
                    bl[c] = __builtin_bit_cast(short, lb);
                }
                acc[j] = __builtin_amdgcn_mfma_f32_16x16x32_bf16(ah, bh, acc[j], 0, 0, 0);
                acc[j] = __builtin_amdgcn_mfma_f32_16x16x32_bf16(ah, bl, acc[j], 0, 0, 0);
                acc[j] = __builtin_amdgcn_mfma_f32_16x16x32_bf16(al, bh, acc[j], 0, 0, 0);
            }
        }
    };

    // ---- prologue: x(0), W(0), x(1)  (12 outstanding per wave) ----
    stage_x(0);
    stage_w(0);
    stage_x(1);

    // ---- main loop: ONE barrier per tile ----
#pragma unroll
    for (int kt = 0; kt < NKT; ++kt) {
        // complete x(kt)+W(kt); leave the 4 newest (stage_x of kt+1) in flight
        if (kt < NKT - 1) asm volatile("s_waitcnt vmcnt(4)" ::: "memory");
        else              asm volatile("s_waitcnt vmcnt(0)" ::: "memory");
        __builtin_amdgcn_s_barrier();          // all waves done with tile kt-1
        __builtin_amdgcn_sched_barrier(0);
        if (kt + 1 < NKT) stage_w(kt + 1);     // may interleave with compute:
                                               // dest buf untouched until NEXT
                                               // barrier (no fence here)
        __builtin_amdgcn_s_setprio(1);
        compute(kt);
        __builtin_amdgcn_s_setprio(0);
        __builtin_amdgcn_sched_barrier(0);
        if (kt + 2 < NKT) stage_x(kt + 2);     // buf (kt+2)%3 free since barrier
    }

    __syncthreads();   // full fence before reusing x buffers

    float* sLog = (float*)SL;                  // [0,16K)
    int* lh = (int*)(SL + 16384);              // xs1 region, dead now

    if (tid < NE) lh[tid] = 0;
    __syncthreads();

    // ---- fused epilogue: per-token softmax top-1 (each wave: its 16 tokens)
#pragma unroll
    for (int r = 0; r < 4; ++r) {
        const int tl = wv * 16 + kq * 4 + r;   // token local to block (0..63)
        float val[4];
#pragma unroll
        for (int j = 0; j < 4; ++j) val[j] = acc[j][r];

        // local argmax over j (ascending j + strict > keeps lowest expert)
        float m = val[0];
        int mi = lr;
#pragma unroll
        for (int j = 1; j < 4; ++j) {
            if (val[j] > m) { m = val[j]; mi = j * 16 + lr; }
        }
        // butterfly across the 16 lanes of this fragment-row group
#pragma unroll
        for (int off = 1; off < 16; off <<= 1) {
            float m2 = __shfl_xor(m, off);
            int mi2 = __shfl_xor(mi, off);
            if (m2 > m || (m2 == m && mi2 < mi)) { m = m2; mi = mi2; }
        }
        // softmax denominator
        float s = 0.0f;
#pragma unroll
        for (int j = 0; j < 4; ++j) s += __expf(val[j] - m);
#pragma unroll
        for (int off = 1; off < 16; off <<= 1) s += __shfl_xor(s, off);

        // stage logits in LDS for dense write
#pragma unroll
        for (int j = 0; j < 4; ++j) sLog[tl * NE + j * 16 + lr] = val[j];
        if (lr == 0) {
            idx_ws[tok0 + tl] = mi;
            prob_ws[tok0 + tl] = 1.0f / s;
            atomicAdd(&lh[mi], 1);
        }
    }
    __syncthreads();

    // dense logits write: 4096 floats = 4 passes x 256 thr x float4
    const size_t g0 = (size_t)tok0 * NE;
#pragma unroll
    for (int i = 0; i < 4; ++i) {
        const int fl = i * 1024 + tid * 4;
        *(float4*)&logits[g0 + fl] = *(const float4*)&sLog[fl];
    }
    if (tid < NE) hist[blockIdx.x * NE + tid] = lh[tid];
}

// ---------------------------------------------------------------------------
// K2: output kernel. One block per 64-token chunk (512 blocks x 256 thr):
//   base = sum of this batch's preceding chunk hists (4-wave strided),
//   ordered capacity rank (wave 0, lane = expert, INCLUSIVE <= CAPACITY),
//   dense float4 writes of e_out / p_out (no zero-fill, no RMW).
// ---------------------------------------------------------------------------
__global__ __launch_bounds__(256) void k_out(const int* __restrict__ idx_ws,
                                             const float* __restrict__ prob_ws,
                                             const int* __restrict__ hist,
                                             float* __restrict__ e_out,
                                             float* __restrict__ p_out)
{
    __shared__ int sMi[OCH];
    __shared__ float sPr[OCH];
    __shared__ int sAd[OCH];
    __shared__ int pp[4][NE];

    const int c = blockIdx.x;        // 0..511 == chunk id
    const int b = c >> 7;            // batch (128 chunks per batch)
    const int s = c & 127;           // chunk within batch
    const int t0 = c * OCH;
    const int tid = threadIdx.x;
    const int lane = tid & 63;
    const int wv = tid >> 6;

    if (tid < OCH) {
        sMi[tid] = idx_ws[t0 + tid];
        sPr[tid] = prob_ws[t0 + tid];
    }

    // strided partial sums over the batch's preceding s chunks
    {
        int run = 0;
        const int* hrow = hist + (size_t)(b * CPB) * NE + lane;
        for (int i = wv; i < s; i += 4) run += hrow[i * NE];
        pp[wv][lane] = run;
    }
    __syncthreads();

    if (wv == 0) {
        int run = pp[0][lane] + pp[1][lane] + pp[2][lane] + pp[3][lane];
        for (int j = 0; j < OCH; ++j) {
            if (sMi[j] == lane) { ++run; sAd[j] = (run <= CAPACITY) ? 1 : 0; }
        }
    }
    __syncthreads();

    // dense e/p writes: 4096 floats each = 4 passes x 256 thr x float4
    const size_t g0 = (size_t)t0 * NE;
#pragma unroll
    for (int i = 0; i < 4; ++i) {
        const int fl = i * 1024 + tid * 4;
        const int t = fl >> 6;
        const int e0 = fl & 63;
        const int mi = sMi[t];
        const float pr = sPr[t];
        const int ad = sAd[t];
        float4 ev, pv;
        float* evp = &ev.x;
        float* pvp = &pv.x;
#pragma unroll
        for (int cc = 0; cc < 4; ++cc) {
            const bool hit = (mi == e0 + cc) && ad;
            evp[cc] = hit ? 1.0f : 0.0f;
            pvp[cc] = hit ? pr : 0.0f;
        }
        *(float4*)&e_out[g0 + fl] = ev;
        *(float4*)&p_out[g0 + fl] = pv;
    }
}

// ---------------------------------------------------------------------------
extern "C" void kernel_launch(void* const* d_in, const int* in_sizes, int n_in,
                              void* d_out, int out_size, void* d_ws, size_t ws_size,
                              hipStream_t stream)
{
    const float* x = (const float*)d_in[0];   // [B,S,D] fp32
    const float* W = (const float*)d_in[1];   // [E,D] fp32
    // d_in[2] = top_k (==1), ignored

    float* out = (float*)d_out;
    float* e_out = out;                          // expert_indices as 0.0/1.0
    float* p_out = out + (size_t)NM * NE;        // router_probs
    float* logits = out + 2 * (size_t)NM * NE;   // logits

    char* ws = (char*)d_ws;
    int* idx_ws    = (int*)ws;                                   // 128 KB
    float* prob_ws = (float*)(ws + (size_t)NM * 4);              // 128 KB
    int* hist      = (int*)(ws + (size_t)NM * 8);                // 512*64*4 = 128 KB

    k1_mfma<<<NBLK, 256, 0, stream>>>(x, W, logits, idx_ws, prob_ws, hist);
    k_out<<<NOB, 256, 0, stream>>>(idx_ws, prob_ws, hist, e_out, p_out);
}